// Round 8
// baseline (119.520 us; speedup 1.0000x reference)
//
#include <hip/hip_runtime.h>

#define NC 32
#define DC 16
#define LSEQ 2048

// ---------------------------------------------------------------------------
// k_sum_u: per-block partial column sums of u over 256 l's.
// grid 256 (b = bid>>3, chunk = bid&7), 256 threads. Writes v0p[bid][64].
// ---------------------------------------------------------------------------
__global__ __launch_bounds__(256) void k_sum_u(const float* __restrict__ u,
                                               float* __restrict__ v0p) {
    int b  = blockIdx.x >> 3;
    int l0 = (blockIdx.x & 7) * 256;
    int q  = threadIdx.x & 15;   // float4 column
    int r  = threadIdx.x >> 4;   // row offset 0..15
    const float4* u4 = (const float4*)u;
    float4 acc = {0.f, 0.f, 0.f, 0.f};
#pragma unroll
    for (int j = 0; j < 16; ++j) {
        int l = l0 + r + 16 * j;
        float4 x = u4[(b * LSEQ + l) * 16 + q];
        acc.x += x.x; acc.y += x.y; acc.z += x.z; acc.w += x.w;
    }
    __shared__ float red[16][64];
    red[r][q * 4 + 0] = acc.x;
    red[r][q * 4 + 1] = acc.y;
    red[r][q * 4 + 2] = acc.z;
    red[r][q * 4 + 3] = acc.w;
    __syncthreads();
    if (threadIdx.x < 64) {
        float s = 0.f;
#pragma unroll
        for (int rr = 0; rr < 16; ++rr) s += red[rr][threadIdx.x];
        v0p[blockIdx.x * 64 + threadIdx.x] = s;   // partial, no atomics
    }
}

// ---------------------------------------------------------------------------
// k_caps_final: fold 16 route partials -> v; s = v@W_n; out = L2-normalize(s).
// grid 256 (b = bid>>3, ng = bid&7 -> capsules ng*4..+3), 64 threads.
// (r0-verified code path, FINAL branch only.)
// ---------------------------------------------------------------------------
__global__ __launch_bounds__(64) void k_caps_final(const float* __restrict__ v,
                                                   const float* __restrict__ W,
                                                   float* __restrict__ out) {
    int b  = blockIdx.x >> 3;
    int ng = blockIdx.x & 7;
    int t  = threadIdx.x;
    __shared__ float vS[4][72];
    {
        int row = t >> 4, col4 = t & 15;
        const float4* v4 = (const float4*)v;
        float4 a = {0.f, 0.f, 0.f, 0.f};
#pragma unroll
        for (int ch = 0; ch < 16; ++ch) {
            float4 x = v4[(b * 16 + ch) * 512 + (ng * 4 + row) * 16 + col4];
            a.x += x.x; a.y += x.y; a.z += x.z; a.w += x.w;
        }
        ((float4*)&vS[row][0])[col4] = a;
    }
    __syncthreads();
    int n4 = t >> 4, d = t & 15;
    int n  = ng * 4 + n4;
    const float* vrow = &vS[n4][0];
    float s = 0.f;
#pragma unroll
    for (int i = 0; i < 64; ++i)
        s = fmaf(vrow[i], W[i * (NC * DC) + n * DC + d], s);
    float s2 = s * s;
#pragma unroll
    for (int off = 8; off >= 1; off >>= 1) s2 += __shfl_xor(s2, off, 16);
    out[b * (NC * DC) + n * DC + d] = s / sqrtf(s2 + 1e-7f);
}

// ---------------------------------------------------------------------------
// k_route v8: r6 body (256 thr = 4 waves, 2/SIMD at 2 blocks/CU) + fused caps
// HEAD. grid 512 (b = bid>>4, ch = bid&15 -> 128 l's).
// Head (per-block redundant, no cross-block sync needed — stream order
// guarantees vin complete): fold vin -> vS (LDS), s = v@W, normalize -> oS,
// wtil -> wS (LDS; no global wtil round-trip).
//   ITER0: vin = v0p (8 partials x 64, uniform c -> single 64-vec, x 1/32).
//   else : vin = vpart_prev (16 partials x 2048).
// Body: phase A per-lane 4l x 4n logits (n = lc+8*jj, conflict-free),
// in-register softmax, phase B 4n x 8d V-tile, cross-wave fold, store vpart.
// ---------------------------------------------------------------------------
template <int ITER0>
__global__ __launch_bounds__(256) void k_route(const float* __restrict__ u,
                                               const float* __restrict__ W,
                                               const float* __restrict__ vin,
                                               float* __restrict__ vpart) {
    int b    = blockIdx.x >> 4;
    int ch   = blockIdx.x & 15;
    int l0   = ch * 128;
    int t    = threadIdx.x;
    int w    = t >> 6;
    int lane = t & 63;
    int lr   = lane & 7;   // l = w*32 + lr + 8*i
    int lc   = lane >> 3;  // n = lc + 8*jj
    int dr   = lane & 7;   // phase B: d = dr*8 .. dr*8+7
    int ng   = lane >> 3;  // phase B: n = ng + 8*jj

    __shared__ float uS[128 * 68];        // 34816 B; red[2][2048] overlay later
    __shared__ float wS[32 * 68];         //  8704 B
    __shared__ float cS[128 * 36];        // 18432 B; head vS overlay first
    __shared__ float oS[512];             //  2048 B  (total 64000 B)
    float4* uS4 = (float4*)uS;
    float4* wS4 = (float4*)wS;
    float4* c4  = (float4*)cS;

    // ---- stage u-tile [128][64] (issue before head; coalesced) ----
    const float4* ug = (const float4*)(u + (b * LSEQ + l0) * 64);
#pragma unroll
    for (int r = 0; r < 8; ++r) {
        int idx = t + 256 * r;                 // 0..2047 = row*16 + col4
        uS4[(idx >> 4) * 17 + (idx & 15)] = ug[idx];
    }

    // ---- HEAD H1: fold vin -> vS (in cS) ----
    float* vS = cS;                            // ITER0: [64]; else [32][68]
    if (ITER0) {
        if (t < 64) {
            float s = 0.f;
#pragma unroll
            for (int c = 0; c < 8; ++c) s += vin[(b * 8 + c) * 64 + t];
            vS[t] = s * (1.f / 32.f);
        }
    } else {
        const float4* vp = (const float4*)(vin + b * 16 * 2048);
#pragma unroll
        for (int r = 0; r < 2; ++r) {
            int idx = t + 256 * r;             // 0..511: n = idx>>4, c4 = idx&15
            float4 s = {0.f, 0.f, 0.f, 0.f};
#pragma unroll
            for (int c = 0; c < 16; ++c) {
                float4 x = vp[c * 512 + idx];
                s.x += x.x; s.y += x.y; s.z += x.z; s.w += x.w;
            }
            ((float4*)vS)[(idx >> 4) * 17 + (idx & 15)] = s;
        }
    }
    __syncthreads();

    // ---- HEAD H2: s[n][d] = v[n]@W[:,n*16+d]; L2-normalize -> oS ----
#pragma unroll
    for (int rep = 0; rep < 2; ++rep) {
        int nd = t + 256 * rep;                // n = nd>>4, d = nd&15
        const float* vrow = ITER0 ? vS : vS + (nd >> 4) * 68;
        float s = 0.f;
#pragma unroll 8
        for (int i = 0; i < 64; ++i)
            s = fmaf(vrow[i], W[i * (NC * DC) + nd], s);
        float s2 = s * s;
        s2 += __shfl_xor(s2, 1);
        s2 += __shfl_xor(s2, 2);
        s2 += __shfl_xor(s2, 4);
        s2 += __shfl_xor(s2, 8);
        oS[nd] = s / sqrtf(s2 + 1e-7f);
    }
    __syncthreads();

    // ---- HEAD H3: wS[n][i] = sum_d W[i][n*16+d] * o[n][d] (stride-68) ----
#pragma unroll
    for (int rep = 0; rep < 2; ++rep) {
        int f4 = t + 256 * rep;                // 0..511: n = f4>>4, i4 = f4&15
        int n = f4 >> 4, i4 = f4 & 15;
        const float4* o4 = (const float4*)(oS + n * DC);
        float4 ov0 = o4[0], ov1 = o4[1], ov2 = o4[2], ov3 = o4[3];
        float4 wv;
        float* wvp = (float*)&wv;
#pragma unroll
        for (int k = 0; k < 4; ++k) {
            int i = i4 * 4 + k;
            const float4* wr = (const float4*)(W + i * (NC * DC) + n * DC);
            float4 w0 = wr[0], w1 = wr[1], w2 = wr[2], w3 = wr[3];
            float acc = w0.x * ov0.x + w0.y * ov0.y + w0.z * ov0.z + w0.w * ov0.w;
            acc += w1.x * ov1.x + w1.y * ov1.y + w1.z * ov1.z + w1.w * ov1.w;
            acc += w2.x * ov2.x + w2.y * ov2.y + w2.z * ov2.z + w2.w * ov2.w;
            acc += w3.x * ov3.x + w3.y * ov3.y + w3.z * ov3.z + w3.w * ov3.w;
            wvp[k] = acc;
        }
        wS4[n * 17 + i4] = wv;
    }
    __syncthreads();                           // wS + uS ready

    // ---- phase A: logits (per-lane 4l x 4n register tile) ----
    float acc[4][4];
#pragma unroll
    for (int i = 0; i < 4; ++i)
#pragma unroll
        for (int jj = 0; jj < 4; ++jj) acc[i][jj] = 0.f;
    int arow = w * 32 + lr;
#pragma unroll 4
    for (int k4 = 0; k4 < 16; ++k4) {
        float4 wf[4];
#pragma unroll
        for (int jj = 0; jj < 4; ++jj) wf[jj] = wS4[(lc + 8 * jj) * 17 + k4];
#pragma unroll
        for (int i = 0; i < 4; ++i) {
            float4 a = uS4[(arow + 8 * i) * 17 + k4];
#pragma unroll
            for (int jj = 0; jj < 4; ++jj) {
                acc[i][jj] = fmaf(a.x, wf[jj].x, acc[i][jj]);
                acc[i][jj] = fmaf(a.y, wf[jj].y, acc[i][jj]);
                acc[i][jj] = fmaf(a.z, wf[jj].z, acc[i][jj]);
                acc[i][jj] = fmaf(a.w, wf[jj].w, acc[i][jj]);
            }
        }
    }

    // ---- softmax over n (4 regs x 8 lc-groups) per l-row i ----
#pragma unroll
    for (int i = 0; i < 4; ++i) {
        float m = fmaxf(fmaxf(acc[i][0], acc[i][1]), fmaxf(acc[i][2], acc[i][3]));
        m = fmaxf(m, __shfl_xor(m, 8));
        m = fmaxf(m, __shfl_xor(m, 16));
        m = fmaxf(m, __shfl_xor(m, 32));
        float e0 = __expf(acc[i][0] - m), e1 = __expf(acc[i][1] - m);
        float e2 = __expf(acc[i][2] - m), e3 = __expf(acc[i][3] - m);
        float ss = e0 + e1 + e2 + e3;
        ss += __shfl_xor(ss, 8);
        ss += __shfl_xor(ss, 16);
        ss += __shfl_xor(ss, 32);
        float inv = 1.f / ss;
        float4 cvv = {e0 * inv, e1 * inv, e2 * inv, e3 * inv};
        c4[(arow + 8 * i) * 9 + lc] = cvv;     // xyzw = n = lc, lc+8, lc+16, lc+24
    }
    __syncthreads();

    // ---- phase B: V[n = ng+8jj][d = dr*8..+7] += sum_l c[l][n]*u[l][d] ----
    float vacc[4][8];
#pragma unroll
    for (int jj = 0; jj < 4; ++jj)
#pragma unroll
        for (int k = 0; k < 8; ++k) vacc[jj][k] = 0.f;
#pragma unroll 8
    for (int lrel = 0; lrel < 32; ++lrel) {
        int row = w * 32 + lrel;
        float4 cv = c4[row * 9 + ng];
        const float4* ur = uS4 + row * 17 + dr * 2;
        float4 u0 = ur[0], u1 = ur[1];
        float* cp = (float*)&cv;
#pragma unroll
        for (int jj = 0; jj < 4; ++jj) {
            float c = cp[jj];
            vacc[jj][0] = fmaf(c, u0.x, vacc[jj][0]);
            vacc[jj][1] = fmaf(c, u0.y, vacc[jj][1]);
            vacc[jj][2] = fmaf(c, u0.z, vacc[jj][2]);
            vacc[jj][3] = fmaf(c, u0.w, vacc[jj][3]);
            vacc[jj][4] = fmaf(c, u1.x, vacc[jj][4]);
            vacc[jj][5] = fmaf(c, u1.y, vacc[jj][5]);
            vacc[jj][6] = fmaf(c, u1.z, vacc[jj][6]);
            vacc[jj][7] = fmaf(c, u1.w, vacc[jj][7]);
        }
    }
    __syncthreads();                   // all uS reads done -> overlay red on uS

    // ---- cross-wave fold: waves 1,3 write; 0,2 add; halves fold + store ----
    float* red   = uS;                 // [2][32][64] floats (16 KB)
    float* rbase = red + (w >> 1) * 2048;
    if (w & 1) {
#pragma unroll
        for (int jj = 0; jj < 4; ++jj) {
            float4* rp = (float4*)(rbase + (ng + 8 * jj) * 64 + dr * 8);
            float4 r0 = {vacc[jj][0], vacc[jj][1], vacc[jj][2], vacc[jj][3]};
            float4 r1 = {vacc[jj][4], vacc[jj][5], vacc[jj][6], vacc[jj][7]};
            rp[0] = r0;
            rp[1] = r1;
        }
    }
    __syncthreads();
    if (!(w & 1)) {
#pragma unroll
        for (int jj = 0; jj < 4; ++jj) {
            float4* rp = (float4*)(rbase + (ng + 8 * jj) * 64 + dr * 8);
            float4 r0 = rp[0], r1 = rp[1];
            r0.x += vacc[jj][0]; r0.y += vacc[jj][1];
            r0.z += vacc[jj][2]; r0.w += vacc[jj][3];
            r1.x += vacc[jj][4]; r1.y += vacc[jj][5];
            r1.z += vacc[jj][6]; r1.w += vacc[jj][7];
            rp[0] = r0;
            rp[1] = r1;
        }
    }
    __syncthreads();
    // fold the 2 halves and store the block partial (coalesced)
    float4* red4 = (float4*)red;
    float4* vp4  = (float4*)(vpart + blockIdx.x * 2048);
#pragma unroll
    for (int s = 0; s < 2; ++s) {
        int idx4 = t + 256 * s;               // 0..511
        float4 a  = red4[idx4];
        float4 c2 = red4[512 + idx4];
        float4 o  = {a.x + c2.x, a.y + c2.y, a.z + c2.z, a.w + c2.w};
        vp4[idx4] = o;
    }
}

extern "C" void kernel_launch(void* const* d_in, const int* in_sizes, int n_in,
                              void* d_out, int out_size, void* d_ws, size_t ws_size,
                              hipStream_t stream) {
    const float* u = (const float*)d_in[0];  // [32, 2048, 64] f32
    const float* W = (const float*)d_in[1];  // [1, 64, 512]  f32
    float* out = (float*)d_out;              // [32, 32, 16]  f32
    float* ws  = (float*)d_ws;
    float* v0p = ws;                   // 256*64   = 16384 floats
    float* vpA = ws + 16384;           // 512*2048 = 1048576 floats
    float* vpB = ws + 16384 + 1048576; // 512*2048 = 1048576 floats

    // iter 0 column-sum, then route1 (head: caps0), route2 (head: caps1),
    // final caps. vpart double-buffered: route2's head reads vpA while its
    // body writes vpB (no intra-kernel RAW across blocks).
    k_sum_u<<<256, 256, 0, stream>>>(u, v0p);
    k_route<1><<<512, 256, 0, stream>>>(u, W, v0p, vpA);
    k_route<0><<<512, 256, 0, stream>>>(u, W, vpA, vpB);
    k_caps_final<<<256, 64, 0, stream>>>(vpB, W, out);
}

// Round 9
// 101.953 us; speedup vs baseline: 1.1723x; 1.1723x over previous
//
#include <hip/hip_runtime.h>

#define NC 32
#define DC 16
#define LSEQ 2048

typedef __fp16 h2 __attribute__((ext_vector_type(2)));
union F4H { float4 f; h2 h[4]; };
union H2F2 { h2 h[2]; float2 f; };

__device__ __forceinline__ float fdot2f(h2 a, h2 b, float c) {
#if __has_builtin(__builtin_amdgcn_fdot2)
    return __builtin_amdgcn_fdot2(a, b, c, false);
#else
    return c + (float)a[0] * (float)b[0] + (float)a[1] * (float)b[1];
#endif
}

// ---------------------------------------------------------------------------
// k_sum_u: per-block partial column sums of u over 256 l's. (r6 verbatim)
// grid 256 (b = bid>>3, chunk = bid&7), 256 threads. Writes v0p[bid][64].
// ---------------------------------------------------------------------------
__global__ __launch_bounds__(256) void k_sum_u(const float* __restrict__ u,
                                               float* __restrict__ v0p) {
    int b  = blockIdx.x >> 3;
    int l0 = (blockIdx.x & 7) * 256;
    int q  = threadIdx.x & 15;
    int r  = threadIdx.x >> 4;
    const float4* u4 = (const float4*)u;
    float4 acc = {0.f, 0.f, 0.f, 0.f};
#pragma unroll
    for (int j = 0; j < 16; ++j) {
        int l = l0 + r + 16 * j;
        float4 x = u4[(b * LSEQ + l) * 16 + q];
        acc.x += x.x; acc.y += x.y; acc.z += x.z; acc.w += x.w;
    }
    __shared__ float red[16][64];
    red[r][q * 4 + 0] = acc.x;
    red[r][q * 4 + 1] = acc.y;
    red[r][q * 4 + 2] = acc.z;
    red[r][q * 4 + 3] = acc.w;
    __syncthreads();
    if (threadIdx.x < 64) {
        float s = 0.f;
#pragma unroll
        for (int rr = 0; rr < 16; ++rr) s += red[rr][threadIdx.x];
        v0p[blockIdx.x * 64 + threadIdx.x] = s;
    }
}

// ---------------------------------------------------------------------------
// k_caps: fold partials -> v[b][n][64]; s = v@W_n; o = L2-normalize(s);
// wtil[b][n][i] = (W_n @ o_n)[i]  (unless FINAL: write o to out).
// grid 256 (b = bid>>3, ng = bid&7), 64 threads. r6 verbatim except the
// non-BCAST fold is now 32 chunks (route grid is 1024 = b*32+ch).
// ---------------------------------------------------------------------------
template <bool BCAST, bool FINAL>
__global__ __launch_bounds__(64) void k_caps(const float* __restrict__ v,
                                             const float* __restrict__ W,
                                             float* __restrict__ wtil,
                                             float* __restrict__ out,
                                             float vscale) {
    int b  = blockIdx.x >> 3;
    int ng = blockIdx.x & 7;
    int t  = threadIdx.x;
    __shared__ float vS[4][72];
    __shared__ float oS[4][16];
    if (BCAST) {
        float s = 0.f;
#pragma unroll
        for (int ch = 0; ch < 8; ++ch) s += v[(b * 8 + ch) * 64 + t];
        s *= vscale;
#pragma unroll
        for (int n4 = 0; n4 < 4; ++n4) vS[n4][t] = s;
    } else {
        int row = t >> 4, col4 = t & 15;
        const float4* v4 = (const float4*)v;
        float4 a = {0.f, 0.f, 0.f, 0.f};
#pragma unroll
        for (int ch = 0; ch < 32; ++ch) {
            float4 x = v4[(b * 32 + ch) * 512 + (ng * 4 + row) * 16 + col4];
            a.x += x.x; a.y += x.y; a.z += x.z; a.w += x.w;
        }
        ((float4*)&vS[row][0])[col4] = a;
    }
    __syncthreads();
    int n4 = t >> 4, d = t & 15;
    int n  = ng * 4 + n4;
    const float* vrow = &vS[n4][0];
    float s = 0.f;
#pragma unroll
    for (int i = 0; i < 64; ++i)
        s = fmaf(vrow[i], W[i * (NC * DC) + n * DC + d], s);
    float s2 = s * s;
#pragma unroll
    for (int off = 8; off >= 1; off >>= 1) s2 += __shfl_xor(s2, off, 16);
    float o = s / sqrtf(s2 + 1e-7f);
    if (FINAL) {
        out[b * (NC * DC) + n * DC + d] = o;
    } else {
        oS[n4][d] = o;
        __syncthreads();
        int i4 = t & 15;
        float4 wv;
        float* wvp = (float*)&wv;
#pragma unroll
        for (int k = 0; k < 4; ++k) {
            int i = i4 * 4 + k;
            float acc = 0.f;
#pragma unroll
            for (int dd = 0; dd < 16; ++dd)
                acc = fmaf(W[i * (NC * DC) + n * DC + dd], oS[n4][dd], acc);
            wvp[k] = acc;
        }
        ((float4*)wtil)[(b * (NC * 64) + n * 64 + i4 * 4) >> 2] = wv;
    }
}

// ---------------------------------------------------------------------------
// k_route v9 (f16 tiles + fdot2): grid 1024 (b = bid>>5, ch = bid&31 -> 64
// l's), 256 threads = 4 waves; 23 KB LDS -> 4 blocks/CU resident (grid/256)
// = 4 waves/SIMD. u and wtil live in LDS as f16 PAIRS (half the read insts);
// logits accumulate in f32 via v_dot2_f32_f16. Softmax/c/fold stay f32.
// Wave w owns l-rows [w*16, w*16+16). Phase A per-lane 2l x 4n (n = lc+8*jj,
// conflict-free). Phase B per-lane 4n x 8d over 16 l's; u unpacked f16->f32.
// Fold r6-style: odd waves write red[w>>1], even add, then 4->1 + store.
// ---------------------------------------------------------------------------
__global__ __launch_bounds__(256, 4) void k_route(const float* __restrict__ u,
                                                  const float* __restrict__ wtil,
                                                  float* __restrict__ vpart) {
    int b    = blockIdx.x >> 5;
    int ch   = blockIdx.x & 31;
    int l0   = ch * 64;
    int t    = threadIdx.x;
    int w    = t >> 6;
    int lane = t & 63;
    int lr   = lane & 7;   // l = w*16 + lr + 8*i
    int lc   = lane >> 3;  // n = lc + 8*jj
    int dr   = lane & 7;   // phase B: d = dr*8 .. dr*8+7
    int ng   = lane >> 3;  // phase B: n = ng + 8*jj

    // smem: uA2f [64 rows][36 f-slots] (f16 pairs, 2 d per slot, pad 4),
    //       wS2f [32][36] (f16 pairs), cS [64 rows][36] f32 c.
    // red[2][2048] f32 (4096 floats) overlays smem after phase B.
    __shared__ float smem[5760];          // 23040 B -> 4+ blocks/CU
    float* uA2f = smem;                   // 2304 floats
    float* wS2f = smem + 2304;            // 1152 floats
    float* cS   = smem + 3456;            // 2304 floats
    const float4* uA2_4 = (const float4*)uA2f;   // row stride 9 float4
    const float4* wS2_4 = (const float4*)wS2f;
    float4* c4 = (float4*)cS;             // row stride 9 float4 (36 floats)

    // ---- stage u-tile [64][64] -> f16 pairs (coalesced reads) ----
    const float4* ug = (const float4*)(u + (b * LSEQ + l0) * 64);
#pragma unroll
    for (int r = 0; r < 4; ++r) {
        int idx = t + 256 * r;                 // 0..1023: row = idx>>4, col4
        float4 x = ug[idx];
        H2F2 p;
        p.h[0][0] = (__fp16)x.x; p.h[0][1] = (__fp16)x.y;
        p.h[1][0] = (__fp16)x.z; p.h[1][1] = (__fp16)x.w;
        *(float2*)(uA2f + (idx >> 4) * 36 + (idx & 15) * 2) = p.f;
    }
    // ---- stage wtil-tile [32][64] -> f16 pairs ----
    {
        const float4* wg = (const float4*)(wtil + b * (NC * 64));
#pragma unroll
        for (int r = 0; r < 2; ++r) {
            int idx = t + 256 * r;             // 0..511: n = idx>>4, col4
            float4 x = wg[idx];
            H2F2 p;
            p.h[0][0] = (__fp16)x.x; p.h[0][1] = (__fp16)x.y;
            p.h[1][0] = (__fp16)x.z; p.h[1][1] = (__fp16)x.w;
            *(float2*)(wS2f + (idx >> 4) * 36 + (idx & 15) * 2) = p.f;
        }
    }
    __syncthreads();

    // ---- phase A: logits, per-lane 2l x 4n, 8 k's per b128 via fdot2 ----
    float acc[2][4];
#pragma unroll
    for (int i = 0; i < 2; ++i)
#pragma unroll
        for (int jj = 0; jj < 4; ++jj) acc[i][jj] = 0.f;
    int arow = w * 16 + lr;
#pragma unroll
    for (int k8 = 0; k8 < 8; ++k8) {
        F4H wf[4];
#pragma unroll
        for (int jj = 0; jj < 4; ++jj) wf[jj].f = wS2_4[(lc + 8 * jj) * 9 + k8];
#pragma unroll
        for (int i = 0; i < 2; ++i) {
            F4H av;
            av.f = uA2_4[(arow + 8 * i) * 9 + k8];
#pragma unroll
            for (int jj = 0; jj < 4; ++jj) {
#pragma unroll
                for (int m = 0; m < 4; ++m)
                    acc[i][jj] = fdot2f(av.h[m], wf[jj].h[m], acc[i][jj]);
            }
        }
    }

    // ---- softmax over n (4 regs x 8 lc-groups) per l-row i ----
#pragma unroll
    for (int i = 0; i < 2; ++i) {
        float m = fmaxf(fmaxf(acc[i][0], acc[i][1]), fmaxf(acc[i][2], acc[i][3]));
        m = fmaxf(m, __shfl_xor(m, 8));
        m = fmaxf(m, __shfl_xor(m, 16));
        m = fmaxf(m, __shfl_xor(m, 32));
        float e0 = __expf(acc[i][0] - m), e1 = __expf(acc[i][1] - m);
        float e2 = __expf(acc[i][2] - m), e3 = __expf(acc[i][3] - m);
        float ss = e0 + e1 + e2 + e3;
        ss += __shfl_xor(ss, 8);
        ss += __shfl_xor(ss, 16);
        ss += __shfl_xor(ss, 32);
        float inv = 1.f / ss;
        float4 cvv = {e0 * inv, e1 * inv, e2 * inv, e3 * inv};
        c4[(arow + 8 * i) * 9 + lc] = cvv;     // xyzw = n = lc, lc+8, lc+16, lc+24
    }
    __syncthreads();

    // ---- phase B: V[n = ng+8jj][d = dr*8..+7] += sum_l c[l][n]*u[l][d] ----
    float vacc[4][8];
#pragma unroll
    for (int jj = 0; jj < 4; ++jj)
#pragma unroll
        for (int k = 0; k < 8; ++k) vacc[jj][k] = 0.f;
#pragma unroll 8
    for (int lrel = 0; lrel < 16; ++lrel) {
        int row = w * 16 + lrel;
        float4 cv = c4[row * 9 + ng];
        F4H uu;
        uu.f = *(const float4*)(uA2f + row * 36 + dr * 4);  // d = dr*8..dr*8+7
        float uf[8];
#pragma unroll
        for (int k = 0; k < 4; ++k) {
            uf[2 * k + 0] = (float)uu.h[k][0];
            uf[2 * k + 1] = (float)uu.h[k][1];
        }
        float* cp = (float*)&cv;
#pragma unroll
        for (int jj = 0; jj < 4; ++jj) {
            float c = cp[jj];
#pragma unroll
            for (int k = 0; k < 8; ++k)
                vacc[jj][k] = fmaf(c, uf[k], vacc[jj][k]);
        }
    }
    __syncthreads();                   // all uA2/cS reads done -> overlay red

    // ---- cross-wave fold: waves 1,3 write; 0,2 add; halves fold + store ----
    float* red   = smem;               // [2][32][64] floats (16 KB <= 23 KB)
    float* rbase = red + (w >> 1) * 2048;
    if (w & 1) {
#pragma unroll
        for (int jj = 0; jj < 4; ++jj) {
            float4* rp = (float4*)(rbase + (ng + 8 * jj) * 64 + dr * 8);
            float4 r0 = {vacc[jj][0], vacc[jj][1], vacc[jj][2], vacc[jj][3]};
            float4 r1 = {vacc[jj][4], vacc[jj][5], vacc[jj][6], vacc[jj][7]};
            rp[0] = r0;
            rp[1] = r1;
        }
    }
    __syncthreads();
    if (!(w & 1)) {
#pragma unroll
        for (int jj = 0; jj < 4; ++jj) {
            float4* rp = (float4*)(rbase + (ng + 8 * jj) * 64 + dr * 8);
            float4 r0 = rp[0], r1 = rp[1];
            r0.x += vacc[jj][0]; r0.y += vacc[jj][1];
            r0.z += vacc[jj][2]; r0.w += vacc[jj][3];
            r1.x += vacc[jj][4]; r1.y += vacc[jj][5];
            r1.z += vacc[jj][6]; r1.w += vacc[jj][7];
            rp[0] = r0;
            rp[1] = r1;
        }
    }
    __syncthreads();
    // fold the 2 pair-partials and store the block partial (coalesced)
    float4* red4 = (float4*)red;
    float4* vp4  = (float4*)(vpart + blockIdx.x * 2048);
#pragma unroll
    for (int s = 0; s < 2; ++s) {
        int idx4 = t + 256 * s;               // 0..511
        float4 a  = red4[idx4];
        float4 c2 = red4[512 + idx4];
        float4 o  = {a.x + c2.x, a.y + c2.y, a.z + c2.z, a.w + c2.w};
        vp4[idx4] = o;
    }
}

extern "C" void kernel_launch(void* const* d_in, const int* in_sizes, int n_in,
                              void* d_out, int out_size, void* d_ws, size_t ws_size,
                              hipStream_t stream) {
    const float* u = (const float*)d_in[0];  // [32, 2048, 64] f32
    const float* W = (const float*)d_in[1];  // [1, 64, 512]  f32
    float* out = (float*)d_out;              // [32, 32, 16]  f32
    float* ws  = (float*)d_ws;
    float* v0p   = ws;                 // 256*64       = 16384 floats
    float* wt    = ws + 16384;         // 32*32*64     = 65536 floats
    float* vpart = ws + 16384 + 65536; // 1024*2048    = 2097152 floats (8 MB)

    // iter 0: uniform c = 1/32 -> column sum
    k_sum_u<<<256, 256, 0, stream>>>(u, v0p);
    k_caps<true, false><<<256, 64, 0, stream>>>(v0p, W, wt, nullptr, 1.0f / 32.0f);
    // iter 1
    k_route<<<1024, 256, 0, stream>>>(u, wt, vpart);
    k_caps<false, false><<<256, 64, 0, stream>>>(vpart, W, wt, nullptr, 1.0f);
    // iter 2
    k_route<<<1024, 256, 0, stream>>>(u, wt, vpart);
    k_caps<false, true><<<256, 64, 0, stream>>>(vpart, W, nullptr, out, 1.0f);
}